// Round 1
// baseline (1224.107 us; speedup 1.0000x reference)
//
#include <hip/hip_runtime.h>
#include <hip/hip_bf16.h>
#include <math.h>

// Graph transformer: 2x TransformerConv (PyG-style), f32 throughout.
// Layer1: H=8,C=8 concat -> 64 + skip, ELU. Layer2: H=1,C=64 + skip, log_softmax.

__device__ inline void atomicMaxFloat(float* addr, float val) {
    // works for any mix of signs given init = -inf
    if (val >= 0.0f) atomicMax((int*)addr, __float_as_int(val));
    else             atomicMin((unsigned int*)addr, __float_as_uint(val));
}

// Fused 4-matrix GEMM: out[node][0:256] = [X@W0+b0 | X@W1+b1 | X@W2+b2 | X@W3+b3]
// Block: 256 threads, 8 nodes per block. K = input dim (512 or 64).
__global__ void gemm4(const float* __restrict__ X, int n, int K,
                      const float* __restrict__ W0, const float* __restrict__ b0,
                      const float* __restrict__ W1, const float* __restrict__ b1,
                      const float* __restrict__ W2, const float* __restrict__ b2,
                      const float* __restrict__ W3, const float* __restrict__ b3,
                      float* __restrict__ out) {
    __shared__ float xs[8][512];
    const int tid = threadIdx.x;
    const int node0 = blockIdx.x * 8;
    const int k4 = K >> 2;
    const float4* Xv = (const float4*)X;
    for (int i = tid; i < 8 * k4; i += 256) {
        int row = i / k4, cc = i % k4;
        int node = node0 + row;
        float4 val = make_float4(0.f, 0.f, 0.f, 0.f);
        if (node < n) val = Xv[(size_t)node * k4 + cc];
        *(float4*)&xs[row][cc * 4] = val;
    }
    __syncthreads();
    const int which = tid >> 6, c = tid & 63;
    const float* W = (which == 0) ? W0 : (which == 1) ? W1 : (which == 2) ? W2 : W3;
    const float* b = (which == 0) ? b0 : (which == 1) ? b1 : (which == 2) ? b2 : b3;
    float acc[8];
    float bias = b[c];
#pragma unroll
    for (int r = 0; r < 8; ++r) acc[r] = bias;
    for (int d = 0; d < K; ++d) {
        float w = W[d * 64 + c];
#pragma unroll
        for (int r = 0; r < 8; ++r) acc[r] += xs[r][d] * w;
    }
#pragma unroll
    for (int r = 0; r < 8; ++r) {
        int node = node0 + r;
        if (node < n) out[(size_t)node * 256 + tid] = acc[r];
    }
}

// init amax=-inf, denom=0, agg=0
__global__ void init_bufs(float* __restrict__ amax, float* __restrict__ denom,
                          float* __restrict__ agg, int nAmax, int nAgg) {
    int i = blockIdx.x * 256 + threadIdx.x;
    if (i < nAmax) { amax[i] = -INFINITY; denom[i] = 0.f; }
    if (i < nAgg) agg[i] = 0.f;
}

// Layer1 logits: one thread per edge, 8 heads of dot8 / sqrt(8)
__global__ void edge_logits1(const float* __restrict__ qkvs,
                             const int* __restrict__ src, const int* __restrict__ dst,
                             int nE, float* __restrict__ alpha, float* __restrict__ amax) {
    int e = blockIdx.x * 256 + threadIdx.x;
    if (e >= nE) return;
    int s = src[e], d = dst[e];
    const float4* qd = (const float4*)(qkvs + (size_t)d * 256);        // q at cols 0..63
    const float4* ks = (const float4*)(qkvs + (size_t)s * 256 + 64);   // k at cols 64..127
#pragma unroll
    for (int h = 0; h < 8; ++h) {
        float4 q0 = qd[h * 2], q1 = qd[h * 2 + 1];
        float4 k0 = ks[h * 2], k1 = ks[h * 2 + 1];
        float dot = q0.x * k0.x + q0.y * k0.y + q0.z * k0.z + q0.w * k0.w
                  + q1.x * k1.x + q1.y * k1.y + q1.z * k1.z + q1.w * k1.w;
        dot *= 0.35355339059327373f; // 1/sqrt(8)
        alpha[(size_t)e * 8 + h] = dot;
        atomicMaxFloat(&amax[(size_t)d * 8 + h], dot);
    }
}

// Layer2 logits: one thread per edge, dot64 / 8
__global__ void edge_logits2(const float* __restrict__ qkvs,
                             const int* __restrict__ src, const int* __restrict__ dst,
                             int nE, float* __restrict__ alpha, float* __restrict__ amax) {
    int e = blockIdx.x * 256 + threadIdx.x;
    if (e >= nE) return;
    int s = src[e], d = dst[e];
    const float4* qd = (const float4*)(qkvs + (size_t)d * 256);
    const float4* ks = (const float4*)(qkvs + (size_t)s * 256 + 64);
    float dot = 0.f;
#pragma unroll
    for (int i = 0; i < 16; ++i) {
        float4 q = qd[i], k = ks[i];
        dot += q.x * k.x + q.y * k.y + q.z * k.z + q.w * k.w;
    }
    dot *= 0.125f; // 1/sqrt(64)
    alpha[e] = dot;
    atomicMaxFloat(&amax[d], dot);
}

// ex = exp(alpha - amax[dst]); alpha <- ex; denom[dst] += ex.  One thread per (edge,head).
__global__ void edge_ex(const int* __restrict__ dst, float* __restrict__ alpha,
                        const float* __restrict__ amax, float* __restrict__ denom,
                        int nE, int H) {
    long long i = (long long)blockIdx.x * 256 + threadIdx.x;
    if (i >= (long long)nE * H) return;
    int e = (int)(i / H), h = (int)(i - (long long)e * H);
    int d = dst[e];
    float v = expf(alpha[i] - amax[(size_t)d * H + h]);
    alpha[i] = v;
    atomicAdd(&denom[(size_t)d * H + h], v);
}

// Weighted scatter-add of V: one wave (64 lanes) per edge, lane = channel.
__global__ void edge_agg(const float* __restrict__ qkvs, const float* __restrict__ ex,
                         const float* __restrict__ denom,
                         const int* __restrict__ src, const int* __restrict__ dst,
                         float* __restrict__ agg, int nE, int H) {
    int e = blockIdx.x * 4 + (threadIdx.x >> 6);
    if (e >= nE) return;
    int lane = threadIdx.x & 63;
    int s = src[e], d = dst[e];
    int h = (H == 8) ? (lane >> 3) : 0;
    float a = ex[(size_t)e * H + h] / (denom[(size_t)d * H + h] + 1e-16f);
    float v = qkvs[(size_t)s * 256 + 128 + lane]; // v at cols 128..191
    atomicAdd(&agg[(size_t)d * 64 + lane], a * v);
}

// h1 = ELU(agg + skip)  (skip stored at qkvs cols 192..255)
__global__ void finish1(const float* __restrict__ agg, const float* __restrict__ qkvs,
                        float* __restrict__ h1, int n64) {
    int i = blockIdx.x * 256 + threadIdx.x;
    if (i >= n64) return;
    int node = i >> 6, c = i & 63;
    float t = agg[i] + qkvs[(size_t)node * 256 + 192 + c];
    h1[i] = (t > 0.f) ? t : expm1f(t);
}

// out = log_softmax(agg + skip) per node; one wave per node.
__global__ void final_out(const float* __restrict__ agg, const float* __restrict__ qkvs,
                          float* __restrict__ out, int n) {
    int node = blockIdx.x * 4 + (threadIdx.x >> 6);
    if (node >= n) return;
    int lane = threadIdx.x & 63;
    float t = agg[(size_t)node * 64 + lane] + qkvs[(size_t)node * 256 + 192 + lane];
    float m = t;
#pragma unroll
    for (int mask = 32; mask >= 1; mask >>= 1) m = fmaxf(m, __shfl_xor(m, mask, 64));
    float e = expf(t - m);
    float ssum = e;
#pragma unroll
    for (int mask = 32; mask >= 1; mask >>= 1) ssum += __shfl_xor(ssum, mask, 64);
    out[(size_t)node * 64 + lane] = (t - m) - logf(ssum);
}

extern "C" void kernel_launch(void* const* d_in, const int* in_sizes, int n_in,
                              void* d_out, int out_size, void* d_ws, size_t ws_size,
                              hipStream_t stream) {
    const int N = in_sizes[0] / 512;     // 50000
    const int E = in_sizes[1] / 2;       // 800000
    const float* x   = (const float*)d_in[0];
    const int*   ei  = (const int*)d_in[1];
    const int* src = ei;         // edge_index[0]
    const int* dst = ei + E;     // edge_index[1]
    const float *Wq1 = (const float*)d_in[2],  *bq1 = (const float*)d_in[3];
    const float *Wk1 = (const float*)d_in[4],  *bk1 = (const float*)d_in[5];
    const float *Wv1 = (const float*)d_in[6],  *bv1 = (const float*)d_in[7];
    const float *Ws1 = (const float*)d_in[8],  *bs1 = (const float*)d_in[9];
    const float *Wq2 = (const float*)d_in[10], *bq2 = (const float*)d_in[11];
    const float *Wk2 = (const float*)d_in[12], *bk2 = (const float*)d_in[13];
    const float *Wv2 = (const float*)d_in[14], *bv2 = (const float*)d_in[15];
    const float *Ws2 = (const float*)d_in[16], *bs2 = (const float*)d_in[17];

    float* ws = (float*)d_ws;
    // workspace layout (floats)
    const size_t OFF_QKVS = 0;                            // N*256 = 12.8M
    const size_t OFF_H1   = OFF_QKVS + (size_t)N * 256;   // N*64  = 3.2M
    const size_t OFF_ALPH = OFF_H1   + (size_t)N * 64;    // E*8   = 6.4M
    const size_t OFF_AMAX = OFF_ALPH + (size_t)E * 8;     // N*8
    const size_t OFF_DEN  = OFF_AMAX + (size_t)N * 8;     // N*8
    const size_t OFF_AGG  = OFF_DEN  + (size_t)N * 8;     // N*64
    const size_t TOTAL    = OFF_AGG  + (size_t)N * 64;
    if (ws_size < TOTAL * sizeof(float)) return; // insufficient scratch -> fail loudly

    float* qkvs  = ws + OFF_QKVS;
    float* h1    = ws + OFF_H1;
    float* alpha = ws + OFF_ALPH;
    float* amax  = ws + OFF_AMAX;
    float* denom = ws + OFF_DEN;
    float* agg   = ws + OFF_AGG;
    float* out   = (float*)d_out;

    const int n64 = N * 64;

    // ---------- Layer 1 ----------
    gemm4<<<(N + 7) / 8, 256, 0, stream>>>(x, N, 512,
        Wq1, bq1, Wk1, bk1, Wv1, bv1, Ws1, bs1, qkvs);
    init_bufs<<<(n64 + 255) / 256, 256, 0, stream>>>(amax, denom, agg, N * 8, n64);
    edge_logits1<<<(E + 255) / 256, 256, 0, stream>>>(qkvs, src, dst, E, alpha, amax);
    {
        long long tot = (long long)E * 8;
        edge_ex<<<(int)((tot + 255) / 256), 256, 0, stream>>>(dst, alpha, amax, denom, E, 8);
    }
    edge_agg<<<(E + 3) / 4, 256, 0, stream>>>(qkvs, alpha, denom, src, dst, agg, E, 8);
    finish1<<<(n64 + 255) / 256, 256, 0, stream>>>(agg, qkvs, h1, n64);

    // ---------- Layer 2 ----------
    gemm4<<<(N + 7) / 8, 256, 0, stream>>>(h1, N, 64,
        Wq2, bq2, Wk2, bk2, Wv2, bv2, Ws2, bs2, qkvs);
    init_bufs<<<(n64 + 255) / 256, 256, 0, stream>>>(amax, denom, agg, N, n64);
    edge_logits2<<<(E + 255) / 256, 256, 0, stream>>>(qkvs, src, dst, E, alpha, amax);
    edge_ex<<<(E + 255) / 256, 256, 0, stream>>>(dst, alpha, amax, denom, E, 1);
    edge_agg<<<(E + 3) / 4, 256, 0, stream>>>(qkvs, alpha, denom, src, dst, agg, E, 1);
    final_out<<<(N + 3) / 4, 256, 0, stream>>>(agg, qkvs, out, N);
}

// Round 2
// 979.758 us; speedup vs baseline: 1.2494x; 1.2494x over previous
//
#include <hip/hip_runtime.h>
#include <hip/hip_bf16.h>
#include <math.h>

// Graph transformer: 2x TransformerConv (PyG-style).
// GEMMs in bf16 MFMA (16x16x32), edge pipeline f32.

typedef __attribute__((ext_vector_type(4))) float f32x4;
typedef __attribute__((ext_vector_type(8))) short bf16x8;
typedef __attribute__((ext_vector_type(8))) unsigned short u16x8;

__device__ inline unsigned short f2bf(float f) {
    union { float f; unsigned u; } v; v.f = f;
    unsigned r = (v.u + 0x7fffu + ((v.u >> 16) & 1u)) >> 16;
    return (unsigned short)r;
}

__device__ inline void atomicMaxFloat(float* addr, float val) {
    if (val >= 0.0f) atomicMax((int*)addr, __float_as_int(val));
    else             atomicMin((unsigned int*)addr, __float_as_uint(val));
}

// Build Bt[256][K] bf16 (transposed concat of 4 weight mats) + bias[256].
__global__ void prep_w(const float* __restrict__ W0, const float* __restrict__ b0,
                       const float* __restrict__ W1, const float* __restrict__ b1,
                       const float* __restrict__ W2, const float* __restrict__ b2,
                       const float* __restrict__ W3, const float* __restrict__ b3,
                       int K, unsigned short* __restrict__ Bt, float* __restrict__ bias) {
    int i = blockIdx.x * 256 + threadIdx.x;
    int tot = 4 * K * 64;
    if (i < tot) {
        int which = i / (K * 64);
        int rem = i - which * K * 64;
        int k = rem >> 6, n = rem & 63;
        const float* W = (which == 0) ? W0 : (which == 1) ? W1 : (which == 2) ? W2 : W3;
        Bt[(size_t)(which * 64 + n) * K + k] = f2bf(W[k * 64 + n]);
    }
    if (i < 256) {
        int which = i >> 6;
        const float* b = (which == 0) ? b0 : (which == 1) ? b1 : (which == 2) ? b2 : b3;
        bias[i] = b[i & 63];
    }
}

// MFMA GEMM: out[M][256] f32 = A[M][K] @ Bt^T + bias.
// A is f32 (converted to bf16 while staging) or bf16, per ABF16.
// Block: 256 thr = 4 waves; BM=64; wave w owns cols w*64..w*64+63.
template<int KSTEPS, bool ABF16>
__global__ __launch_bounds__(256) void gemm_mfma(const void* __restrict__ Av, int M,
                                                 const unsigned short* __restrict__ Bt,
                                                 const float* __restrict__ bias,
                                                 float* __restrict__ out) {
    constexpr int K = KSTEPS * 64;
    __shared__ unsigned short As[64][72];   // 64x64 bf16 tile, padded stride
    const int tid = threadIdx.x;
    const int lane = tid & 63;
    const int w = tid >> 6;
    const int node0 = blockIdx.x * 64;
    const int r16 = lane & 15, g = lane >> 4;

    f32x4 acc[4][4] = {};

    const int srow = tid >> 2;          // staging row 0..63
    const int sc0 = (tid & 3) * 16;     // staging col 0,16,32,48

    for (int ks = 0; ks < KSTEPS; ++ks) {
        // ---- stage A tile [64][64] bf16 ----
        {
            int node = node0 + srow;
            unsigned short t[16];
            if (ABF16) {
                u16x8 a0 = {}, a1 = {};
                if (node < M) {
                    const u16x8* p = (const u16x8*)((const unsigned short*)Av + (size_t)node * K + ks * 64 + sc0);
                    a0 = p[0]; a1 = p[1];
                }
#pragma unroll
                for (int j = 0; j < 8; ++j) { t[j] = a0[j]; t[8 + j] = a1[j]; }
            } else {
                float4 f0 = {}, f1 = {}, f2 = {}, f3 = {};
                if (node < M) {
                    const float4* p = (const float4*)((const float*)Av + (size_t)node * K + ks * 64 + sc0);
                    f0 = p[0]; f1 = p[1]; f2 = p[2]; f3 = p[3];
                }
                t[0] = f2bf(f0.x); t[1] = f2bf(f0.y); t[2] = f2bf(f0.z); t[3] = f2bf(f0.w);
                t[4] = f2bf(f1.x); t[5] = f2bf(f1.y); t[6] = f2bf(f1.z); t[7] = f2bf(f1.w);
                t[8] = f2bf(f2.x); t[9] = f2bf(f2.y); t[10] = f2bf(f2.z); t[11] = f2bf(f2.w);
                t[12] = f2bf(f3.x); t[13] = f2bf(f3.y); t[14] = f2bf(f3.z); t[15] = f2bf(f3.w);
            }
            u16x8 w0, w1;
#pragma unroll
            for (int j = 0; j < 8; ++j) { w0[j] = t[j]; w1[j] = t[8 + j]; }
            *(u16x8*)&As[srow][sc0] = w0;
            *(u16x8*)&As[srow][sc0 + 8] = w1;
        }
        __syncthreads();

        // ---- MFMA over the 64-wide K tile ----
#pragma unroll
        for (int kk = 0; kk < 2; ++kk) {
            bf16x8 afr[4];
#pragma unroll
            for (int mi = 0; mi < 4; ++mi)
                afr[mi] = *(const bf16x8*)&As[mi * 16 + r16][kk * 32 + g * 8];
#pragma unroll
            for (int ni = 0; ni < 4; ++ni) {
                bf16x8 bfr = *(const bf16x8*)&Bt[(size_t)(w * 64 + ni * 16 + r16) * K + ks * 64 + kk * 32 + g * 8];
#pragma unroll
                for (int mi = 0; mi < 4; ++mi)
                    acc[mi][ni] = __builtin_amdgcn_mfma_f32_16x16x32_bf16(afr[mi], bfr, acc[mi][ni], 0, 0, 0);
            }
        }
        __syncthreads();
    }

    // ---- epilogue: bias + store f32 ----
#pragma unroll
    for (int mi = 0; mi < 4; ++mi) {
#pragma unroll
        for (int r = 0; r < 4; ++r) {
            int row = node0 + mi * 16 + g * 4 + r;
            if (row < M) {
                size_t o = (size_t)row * 256 + w * 64;
#pragma unroll
                for (int ni = 0; ni < 4; ++ni)
                    out[o + ni * 16 + r16] = acc[mi][ni][r] + bias[w * 64 + ni * 16 + r16];
            }
        }
    }
}

// init amax=-inf, denom=0, agg=0
__global__ void init_bufs(float* __restrict__ amax, float* __restrict__ denom,
                          float* __restrict__ agg, int nAmax, int nAgg) {
    int i = blockIdx.x * 256 + threadIdx.x;
    if (i < nAmax) { amax[i] = -INFINITY; denom[i] = 0.f; }
    if (i < nAgg) agg[i] = 0.f;
}

// Layer1 logits: one thread per edge, 8 heads of dot8 / sqrt(8)
__global__ void edge_logits1(const float* __restrict__ qkvs,
                             const int* __restrict__ src, const int* __restrict__ dst,
                             int nE, float* __restrict__ alpha, float* __restrict__ amax) {
    int e = blockIdx.x * 256 + threadIdx.x;
    if (e >= nE) return;
    int s = src[e], d = dst[e];
    const float4* qd = (const float4*)(qkvs + (size_t)d * 256);
    const float4* ks = (const float4*)(qkvs + (size_t)s * 256 + 64);
#pragma unroll
    for (int h = 0; h < 8; ++h) {
        float4 q0 = qd[h * 2], q1 = qd[h * 2 + 1];
        float4 k0 = ks[h * 2], k1 = ks[h * 2 + 1];
        float dot = q0.x * k0.x + q0.y * k0.y + q0.z * k0.z + q0.w * k0.w
                  + q1.x * k1.x + q1.y * k1.y + q1.z * k1.z + q1.w * k1.w;
        dot *= 0.35355339059327373f;
        alpha[(size_t)e * 8 + h] = dot;
        atomicMaxFloat(&amax[(size_t)d * 8 + h], dot);
    }
}

// Layer2 logits: one thread per edge, dot64 / 8
__global__ void edge_logits2(const float* __restrict__ qkvs,
                             const int* __restrict__ src, const int* __restrict__ dst,
                             int nE, float* __restrict__ alpha, float* __restrict__ amax) {
    int e = blockIdx.x * 256 + threadIdx.x;
    if (e >= nE) return;
    int s = src[e], d = dst[e];
    const float4* qd = (const float4*)(qkvs + (size_t)d * 256);
    const float4* ks = (const float4*)(qkvs + (size_t)s * 256 + 64);
    float dot = 0.f;
#pragma unroll
    for (int i = 0; i < 16; ++i) {
        float4 q = qd[i], k = ks[i];
        dot += q.x * k.x + q.y * k.y + q.z * k.z + q.w * k.w;
    }
    dot *= 0.125f;
    alpha[e] = dot;
    atomicMaxFloat(&amax[d], dot);
}

// ex = exp(alpha - amax[dst]); alpha <- ex; denom[dst] += ex.
__global__ void edge_ex(const int* __restrict__ dst, float* __restrict__ alpha,
                        const float* __restrict__ amax, float* __restrict__ denom,
                        int nE, int H) {
    long long i = (long long)blockIdx.x * 256 + threadIdx.x;
    if (i >= (long long)nE * H) return;
    int e = (int)(i / H), h = (int)(i - (long long)e * H);
    int d = dst[e];
    float v = expf(alpha[i] - amax[(size_t)d * H + h]);
    alpha[i] = v;
    atomicAdd(&denom[(size_t)d * H + h], v);
}

// Weighted scatter-add of V: one wave per edge, lane = channel.
__global__ void edge_agg(const float* __restrict__ qkvs, const float* __restrict__ ex,
                         const float* __restrict__ denom,
                         const int* __restrict__ src, const int* __restrict__ dst,
                         float* __restrict__ agg, int nE, int H) {
    int e = blockIdx.x * 4 + (threadIdx.x >> 6);
    if (e >= nE) return;
    int lane = threadIdx.x & 63;
    int s = src[e], d = dst[e];
    int h = (H == 8) ? (lane >> 3) : 0;
    float a = ex[(size_t)e * H + h] / (denom[(size_t)d * H + h] + 1e-16f);
    float v = qkvs[(size_t)s * 256 + 128 + lane];
    atomicAdd(&agg[(size_t)d * 64 + lane], a * v);
}

// h1 = ELU(agg + skip) -> bf16
__global__ void finish1(const float* __restrict__ agg, const float* __restrict__ qkvs,
                        unsigned short* __restrict__ h1bf, int n64) {
    int i = blockIdx.x * 256 + threadIdx.x;
    if (i >= n64) return;
    int node = i >> 6, c = i & 63;
    float t = agg[i] + qkvs[(size_t)node * 256 + 192 + c];
    float e = (t > 0.f) ? t : expm1f(t);
    h1bf[i] = f2bf(e);
}

// out = log_softmax(agg + skip) per node; one wave per node.
__global__ void final_out(const float* __restrict__ agg, const float* __restrict__ qkvs,
                          float* __restrict__ out, int n) {
    int node = blockIdx.x * 4 + (threadIdx.x >> 6);
    if (node >= n) return;
    int lane = threadIdx.x & 63;
    float t = agg[(size_t)node * 64 + lane] + qkvs[(size_t)node * 256 + 192 + lane];
    float m = t;
#pragma unroll
    for (int mask = 32; mask >= 1; mask >>= 1) m = fmaxf(m, __shfl_xor(m, mask, 64));
    float e = expf(t - m);
    float ssum = e;
#pragma unroll
    for (int mask = 32; mask >= 1; mask >>= 1) ssum += __shfl_xor(ssum, mask, 64);
    out[(size_t)node * 64 + lane] = (t - m) - logf(ssum);
}

extern "C" void kernel_launch(void* const* d_in, const int* in_sizes, int n_in,
                              void* d_out, int out_size, void* d_ws, size_t ws_size,
                              hipStream_t stream) {
    const int N = in_sizes[0] / 512;
    const int E = in_sizes[1] / 2;
    const float* x   = (const float*)d_in[0];
    const int*   ei  = (const int*)d_in[1];
    const int* src = ei;
    const int* dst = ei + E;
    const float *Wq1 = (const float*)d_in[2],  *bq1 = (const float*)d_in[3];
    const float *Wk1 = (const float*)d_in[4],  *bk1 = (const float*)d_in[5];
    const float *Wv1 = (const float*)d_in[6],  *bv1 = (const float*)d_in[7];
    const float *Ws1 = (const float*)d_in[8],  *bs1 = (const float*)d_in[9];
    const float *Wq2 = (const float*)d_in[10], *bq2 = (const float*)d_in[11];
    const float *Wk2 = (const float*)d_in[12], *bk2 = (const float*)d_in[13];
    const float *Wv2 = (const float*)d_in[14], *bv2 = (const float*)d_in[15];
    const float *Ws2 = (const float*)d_in[16], *bs2 = (const float*)d_in[17];

    float* ws = (float*)d_ws;
    // workspace layout (float slots)
    const size_t OFF_QKVS = 0;                              // N*256
    const size_t OFF_ALPH = OFF_QKVS + (size_t)N * 256;     // E*8
    const size_t OFF_AMAX = OFF_ALPH + (size_t)E * 8;       // N*8
    const size_t OFF_DEN  = OFF_AMAX + (size_t)N * 8;       // N*8
    const size_t OFF_AGG  = OFF_DEN  + (size_t)N * 8;       // N*64
    const size_t OFF_H1B  = OFF_AGG  + (size_t)N * 64;      // N*64 ushort = N*32 floats
    const size_t OFF_BT1  = OFF_H1B  + (size_t)N * 32;      // 256*512 ushort = 65536 floats
    const size_t OFF_BT2  = OFF_BT1  + 65536;               // 256*64 ushort = 8192 floats
    const size_t OFF_BI1  = OFF_BT2  + 8192;                // 256
    const size_t OFF_BI2  = OFF_BI1  + 256;                 // 256
    const size_t TOTAL    = OFF_BI2  + 256;
    if (ws_size < TOTAL * sizeof(float)) return;

    float* qkvs  = ws + OFF_QKVS;
    float* alpha = ws + OFF_ALPH;
    float* amax  = ws + OFF_AMAX;
    float* denom = ws + OFF_DEN;
    float* agg   = ws + OFF_AGG;
    unsigned short* h1bf = (unsigned short*)(ws + OFF_H1B);
    unsigned short* bt1  = (unsigned short*)(ws + OFF_BT1);
    unsigned short* bt2  = (unsigned short*)(ws + OFF_BT2);
    float* bias1 = ws + OFF_BI1;
    float* bias2 = ws + OFF_BI2;
    float* out   = (float*)d_out;

    const int n64 = N * 64;
    const int gBlocks = (N + 63) / 64;

    // weight prep (both layers)
    prep_w<<<(4 * 512 * 64 + 255) / 256, 256, 0, stream>>>(
        Wq1, bq1, Wk1, bk1, Wv1, bv1, Ws1, bs1, 512, bt1, bias1);
    prep_w<<<(4 * 64 * 64 + 255) / 256, 256, 0, stream>>>(
        Wq2, bq2, Wk2, bk2, Wv2, bv2, Ws2, bs2, 64, bt2, bias2);

    // ---------- Layer 1 ----------
    gemm_mfma<8, false><<<gBlocks, 256, 0, stream>>>(x, N, bt1, bias1, qkvs);
    init_bufs<<<(n64 + 255) / 256, 256, 0, stream>>>(amax, denom, agg, N * 8, n64);
    edge_logits1<<<(E + 255) / 256, 256, 0, stream>>>(qkvs, src, dst, E, alpha, amax);
    {
        long long tot = (long long)E * 8;
        edge_ex<<<(int)((tot + 255) / 256), 256, 0, stream>>>(dst, alpha, amax, denom, E, 8);
    }
    edge_agg<<<(E + 3) / 4, 256, 0, stream>>>(qkvs, alpha, denom, src, dst, agg, E, 8);
    finish1<<<(n64 + 255) / 256, 256, 0, stream>>>(agg, qkvs, h1bf, n64);

    // ---------- Layer 2 ----------
    gemm_mfma<1, true><<<gBlocks, 256, 0, stream>>>(h1bf, N, bt2, bias2, qkvs);
    init_bufs<<<(n64 + 255) / 256, 256, 0, stream>>>(amax, denom, agg, N, n64);
    edge_logits2<<<(E + 255) / 256, 256, 0, stream>>>(qkvs, src, dst, E, alpha, amax);
    edge_ex<<<(E + 255) / 256, 256, 0, stream>>>(dst, alpha, amax, denom, E, 1);
    edge_agg<<<(E + 3) / 4, 256, 0, stream>>>(qkvs, alpha, denom, src, dst, agg, E, 1);
    final_out<<<(N + 3) / 4, 256, 0, stream>>>(agg, qkvs, out, N);
}

// Round 3
// 462.901 us; speedup vs baseline: 2.6444x; 2.1166x over previous
//
#include <hip/hip_runtime.h>
#include <hip/hip_bf16.h>
#include <math.h>

// Graph transformer: 2x TransformerConv (PyG-style).
// GEMMs in bf16 MFMA; attention fused per-dst-node with online softmax over CSR.

typedef __attribute__((ext_vector_type(4))) float f32x4;
typedef __attribute__((ext_vector_type(8))) short bf16x8;
typedef __attribute__((ext_vector_type(8))) unsigned short u16x8;

__device__ inline unsigned short f2bf(float f) {
    union { float f; unsigned u; } v; v.f = f;
    unsigned r = (v.u + 0x7fffu + ((v.u >> 16) & 1u)) >> 16;
    return (unsigned short)r;
}

// ---------------- weight prep ----------------
__global__ void prep_w(const float* __restrict__ W0, const float* __restrict__ b0,
                       const float* __restrict__ W1, const float* __restrict__ b1,
                       const float* __restrict__ W2, const float* __restrict__ b2,
                       const float* __restrict__ W3, const float* __restrict__ b3,
                       int K, unsigned short* __restrict__ Bt, float* __restrict__ bias) {
    int i = blockIdx.x * 256 + threadIdx.x;
    int tot = 4 * K * 64;
    if (i < tot) {
        int which = i / (K * 64);
        int rem = i - which * K * 64;
        int k = rem >> 6, n = rem & 63;
        const float* W = (which == 0) ? W0 : (which == 1) ? W1 : (which == 2) ? W2 : W3;
        Bt[(size_t)(which * 64 + n) * K + k] = f2bf(W[k * 64 + n]);
    }
    if (i < 256) {
        int which = i >> 6;
        const float* b = (which == 0) ? b0 : (which == 1) ? b1 : (which == 2) ? b2 : b3;
        bias[i] = b[i & 63];
    }
}

// ---------------- MFMA GEMM (unchanged from R2) ----------------
template<int KSTEPS, bool ABF16>
__global__ __launch_bounds__(256) void gemm_mfma(const void* __restrict__ Av, int M,
                                                 const unsigned short* __restrict__ Bt,
                                                 const float* __restrict__ bias,
                                                 float* __restrict__ out) {
    constexpr int K = KSTEPS * 64;
    __shared__ unsigned short As[64][72];
    const int tid = threadIdx.x;
    const int lane = tid & 63;
    const int w = tid >> 6;
    const int node0 = blockIdx.x * 64;
    const int r16 = lane & 15, g = lane >> 4;

    f32x4 acc[4][4] = {};

    const int srow = tid >> 2;
    const int sc0 = (tid & 3) * 16;

    for (int ks = 0; ks < KSTEPS; ++ks) {
        {
            int node = node0 + srow;
            unsigned short t[16];
            if (ABF16) {
                u16x8 a0 = {}, a1 = {};
                if (node < M) {
                    const u16x8* p = (const u16x8*)((const unsigned short*)Av + (size_t)node * K + ks * 64 + sc0);
                    a0 = p[0]; a1 = p[1];
                }
#pragma unroll
                for (int j = 0; j < 8; ++j) { t[j] = a0[j]; t[8 + j] = a1[j]; }
            } else {
                float4 f0 = {}, f1 = {}, f2 = {}, f3 = {};
                if (node < M) {
                    const float4* p = (const float4*)((const float*)Av + (size_t)node * K + ks * 64 + sc0);
                    f0 = p[0]; f1 = p[1]; f2 = p[2]; f3 = p[3];
                }
                t[0] = f2bf(f0.x); t[1] = f2bf(f0.y); t[2] = f2bf(f0.z); t[3] = f2bf(f0.w);
                t[4] = f2bf(f1.x); t[5] = f2bf(f1.y); t[6] = f2bf(f1.z); t[7] = f2bf(f1.w);
                t[8] = f2bf(f2.x); t[9] = f2bf(f2.y); t[10] = f2bf(f2.z); t[11] = f2bf(f2.w);
                t[12] = f2bf(f3.x); t[13] = f2bf(f3.y); t[14] = f2bf(f3.z); t[15] = f2bf(f3.w);
            }
            u16x8 w0, w1;
#pragma unroll
            for (int j = 0; j < 8; ++j) { w0[j] = t[j]; w1[j] = t[8 + j]; }
            *(u16x8*)&As[srow][sc0] = w0;
            *(u16x8*)&As[srow][sc0 + 8] = w1;
        }
        __syncthreads();

#pragma unroll
        for (int kk = 0; kk < 2; ++kk) {
            bf16x8 afr[4];
#pragma unroll
            for (int mi = 0; mi < 4; ++mi)
                afr[mi] = *(const bf16x8*)&As[mi * 16 + r16][kk * 32 + g * 8];
#pragma unroll
            for (int ni = 0; ni < 4; ++ni) {
                bf16x8 bfr = *(const bf16x8*)&Bt[(size_t)(w * 64 + ni * 16 + r16) * K + ks * 64 + kk * 32 + g * 8];
#pragma unroll
                for (int mi = 0; mi < 4; ++mi)
                    acc[mi][ni] = __builtin_amdgcn_mfma_f32_16x16x32_bf16(afr[mi], bfr, acc[mi][ni], 0, 0, 0);
            }
        }
        __syncthreads();
    }

#pragma unroll
    for (int mi = 0; mi < 4; ++mi) {
#pragma unroll
        for (int r = 0; r < 4; ++r) {
            int row = node0 + mi * 16 + g * 4 + r;
            if (row < M) {
                size_t o = (size_t)row * 256 + w * 64;
#pragma unroll
                for (int ni = 0; ni < 4; ++ni)
                    out[o + ni * 16 + r16] = acc[mi][ni][r] + bias[w * 64 + ni * 16 + r16];
            }
        }
    }
}

// ---------------- CSR build ----------------
__global__ void zero2(int* __restrict__ a, int* __restrict__ b, int n) {
    int i = blockIdx.x * 256 + threadIdx.x;
    if (i < n) { a[i] = 0; b[i] = 0; }
}

__global__ void hist_deg(const int* __restrict__ dst, int E, int* __restrict__ deg) {
    int e = blockIdx.x * 256 + threadIdx.x;
    if (e < E) atomicAdd(&deg[dst[e]], 1);
}

// single-block exclusive scan over N (<= 1024*chunk)
__global__ __launch_bounds__(1024) void scan_deg(const int* __restrict__ deg,
                                                 int* __restrict__ rowptr, int N) {
    __shared__ int sums[1024];
    const int t = threadIdx.x;
    const int chunk = (N + 1023) / 1024;
    const int start = t * chunk;
    int s = 0;
    for (int i = 0; i < chunk; ++i) {
        int idx = start + i;
        if (idx < N) s += deg[idx];
    }
    sums[t] = s;
    __syncthreads();
    // Hillis-Steele inclusive scan
    for (int off = 1; off < 1024; off <<= 1) {
        int v = (t >= off) ? sums[t - off] : 0;
        __syncthreads();
        sums[t] += v;
        __syncthreads();
    }
    int offset = (t == 0) ? 0 : sums[t - 1];
    int run = offset;
    for (int i = 0; i < chunk; ++i) {
        int idx = start + i;
        if (idx < N) { rowptr[idx] = run; run += deg[idx]; }
    }
    if (t == 0) rowptr[N] = sums[1023];
}

__global__ void scatter_edges(const int* __restrict__ src, const int* __restrict__ dst, int E,
                              const int* __restrict__ rowptr, int* __restrict__ cursor,
                              int* __restrict__ csr_src) {
    int e = blockIdx.x * 256 + threadIdx.x;
    if (e >= E) return;
    int d = dst[e];
    int slot = rowptr[d] + atomicAdd(&cursor[d], 1);
    csr_src[slot] = src[e];
}

// ---------------- fused attention layers ----------------
// Layer1: H=8,C=8. One wave per dst node, lane = channel (head = lane>>3).
// Online softmax in registers; output = bf16 ELU(att + skip).
__global__ __launch_bounds__(256) void attn1(const float* __restrict__ qkvs,
                                             const int* __restrict__ rowptr,
                                             const int* __restrict__ csr_src,
                                             unsigned short* __restrict__ h1bf, int N) {
    int node = blockIdx.x * 4 + (threadIdx.x >> 6);
    if (node >= N) return;
    int lane = threadIdx.x & 63;
    const float* base = qkvs + (size_t)node * 256;
    float q    = base[lane];
    float skip = base[192 + lane];
    float m = -INFINITY, lsum = 0.f, acc = 0.f;
    const int beg = rowptr[node], end = rowptr[node + 1];
    const float SC = 1.44269504f * 0.35355339059327373f;   // log2(e)/sqrt(8)
    for (int i = beg; i < end; ++i) {
        int s = csr_src[i];
        const float* sb = qkvs + (size_t)s * 256;
        float k = sb[64 + lane];
        float v = sb[128 + lane];
        float p = q * k;
        p += __shfl_xor(p, 1, 64);
        p += __shfl_xor(p, 2, 64);
        p += __shfl_xor(p, 4, 64);
        float x = p * SC;
        float mnew = fmaxf(m, x);
        float corr = exp2f(m - mnew);
        float w = exp2f(x - mnew);
        lsum = lsum * corr + w;
        acc  = acc * corr + w * v;
        m = mnew;
    }
    float t = acc / (lsum + 1e-16f) + skip;
    float e = (t > 0.f) ? t : expm1f(t);
    h1bf[(size_t)node * 64 + lane] = f2bf(e);
}

// Layer2: H=1,C=64. One wave per dst node; fuses final log_softmax.
__global__ __launch_bounds__(256) void attn2(const float* __restrict__ qkvs,
                                             const int* __restrict__ rowptr,
                                             const int* __restrict__ csr_src,
                                             float* __restrict__ out, int N) {
    int node = blockIdx.x * 4 + (threadIdx.x >> 6);
    if (node >= N) return;
    int lane = threadIdx.x & 63;
    const float* base = qkvs + (size_t)node * 256;
    float q    = base[lane];
    float skip = base[192 + lane];
    float m = -INFINITY, lsum = 0.f, acc = 0.f;
    const int beg = rowptr[node], end = rowptr[node + 1];
    const float SC = 1.44269504f * 0.125f;                 // log2(e)/sqrt(64)
    for (int i = beg; i < end; ++i) {
        int s = csr_src[i];
        const float* sb = qkvs + (size_t)s * 256;
        float k = sb[64 + lane];
        float v = sb[128 + lane];
        float p = q * k;
#pragma unroll
        for (int mask = 1; mask <= 32; mask <<= 1) p += __shfl_xor(p, mask, 64);
        float x = p * SC;
        float mnew = fmaxf(m, x);
        float corr = exp2f(m - mnew);
        float w = exp2f(x - mnew);
        lsum = lsum * corr + w;
        acc  = acc * corr + w * v;
        m = mnew;
    }
    float t = acc / (lsum + 1e-16f) + skip;
    // log_softmax across 64 lanes
    float mx = t;
#pragma unroll
    for (int mask = 32; mask >= 1; mask >>= 1) mx = fmaxf(mx, __shfl_xor(mx, mask, 64));
    float ex = expf(t - mx);
    float ss = ex;
#pragma unroll
    for (int mask = 32; mask >= 1; mask >>= 1) ss += __shfl_xor(ss, mask, 64);
    out[(size_t)node * 64 + lane] = (t - mx) - logf(ss);
}

// ---------------- launch ----------------
extern "C" void kernel_launch(void* const* d_in, const int* in_sizes, int n_in,
                              void* d_out, int out_size, void* d_ws, size_t ws_size,
                              hipStream_t stream) {
    const int N = in_sizes[0] / 512;
    const int E = in_sizes[1] / 2;
    const float* x   = (const float*)d_in[0];
    const int*   ei  = (const int*)d_in[1];
    const int* src = ei;
    const int* dst = ei + E;
    const float *Wq1 = (const float*)d_in[2],  *bq1 = (const float*)d_in[3];
    const float *Wk1 = (const float*)d_in[4],  *bk1 = (const float*)d_in[5];
    const float *Wv1 = (const float*)d_in[6],  *bv1 = (const float*)d_in[7];
    const float *Ws1 = (const float*)d_in[8],  *bs1 = (const float*)d_in[9];
    const float *Wq2 = (const float*)d_in[10], *bq2 = (const float*)d_in[11];
    const float *Wk2 = (const float*)d_in[12], *bk2 = (const float*)d_in[13];
    const float *Wv2 = (const float*)d_in[14], *bv2 = (const float*)d_in[15];
    const float *Ws2 = (const float*)d_in[16], *bs2 = (const float*)d_in[17];

    float* ws = (float*)d_ws;
    // workspace layout (float slots)
    const size_t OFF_QKVS = 0;                              // N*256
    const size_t OFF_H1B  = OFF_QKVS + (size_t)N * 256;     // N*64 ushort = N*32 f
    const size_t OFF_BT1  = OFF_H1B  + (size_t)N * 32;      // 65536
    const size_t OFF_BT2  = OFF_BT1  + 65536;               // 8192
    const size_t OFF_BI1  = OFF_BT2  + 8192;                // 256
    const size_t OFF_BI2  = OFF_BI1  + 256;                 // 256
    const size_t OFF_ROWP = OFF_BI2  + 256;                 // N+1 ints
    const size_t OFF_DEG  = OFF_ROWP + (size_t)N + 1;       // N ints
    const size_t OFF_CUR  = OFF_DEG  + (size_t)N;           // N ints
    const size_t OFF_CSRC = OFF_CUR  + (size_t)N;           // E ints
    const size_t TOTAL    = OFF_CSRC + (size_t)E;
    if (ws_size < TOTAL * sizeof(float)) return;

    float* qkvs  = ws + OFF_QKVS;
    unsigned short* h1bf = (unsigned short*)(ws + OFF_H1B);
    unsigned short* bt1  = (unsigned short*)(ws + OFF_BT1);
    unsigned short* bt2  = (unsigned short*)(ws + OFF_BT2);
    float* bias1 = ws + OFF_BI1;
    float* bias2 = ws + OFF_BI2;
    int* rowptr  = (int*)(ws + OFF_ROWP);
    int* deg     = (int*)(ws + OFF_DEG);
    int* cursor  = (int*)(ws + OFF_CUR);
    int* csr_src = (int*)(ws + OFF_CSRC);
    float* out   = (float*)d_out;

    const int gBlocks = (N + 63) / 64;
    const int nBlocks4 = (N + 3) / 4;

    // weight prep
    prep_w<<<(4 * 512 * 64 + 255) / 256, 256, 0, stream>>>(
        Wq1, bq1, Wk1, bk1, Wv1, bv1, Ws1, bs1, 512, bt1, bias1);
    prep_w<<<(4 * 64 * 64 + 255) / 256, 256, 0, stream>>>(
        Wq2, bq2, Wk2, bk2, Wv2, bv2, Ws2, bs2, 64, bt2, bias2);

    // CSR build (shared by both layers)
    zero2<<<(N + 255) / 256, 256, 0, stream>>>(deg, cursor, N);
    hist_deg<<<(E + 255) / 256, 256, 0, stream>>>(dst, E, deg);
    scan_deg<<<1, 1024, 0, stream>>>(deg, rowptr, N);
    scatter_edges<<<(E + 255) / 256, 256, 0, stream>>>(src, dst, E, rowptr, cursor, csr_src);

    // ---------- Layer 1 ----------
    gemm_mfma<8, false><<<gBlocks, 256, 0, stream>>>(x, N, bt1, bias1, qkvs);
    attn1<<<nBlocks4, 256, 0, stream>>>(qkvs, rowptr, csr_src, h1bf, N);

    // ---------- Layer 2 ----------
    gemm_mfma<1, true><<<gBlocks, 256, 0, stream>>>(h1bf, N, bt2, bias2, qkvs);
    attn2<<<nBlocks4, 256, 0, stream>>>(qkvs, rowptr, csr_src, out, N);
}